// Round 2
// baseline (694.212 us; speedup 1.0000x reference)
//
#include <hip/hip_runtime.h>
#include <hip/hip_bf16.h>

typedef __attribute__((ext_vector_type(8))) short short8;
typedef __attribute__((ext_vector_type(4))) float float4v;

#define BM 128
#define BK 32
#define LDSK 40   // fallback-path padded row (2-way bank aliasing = free)

struct alignas(8) BF4 { unsigned short x, y, z, w; };
struct alignas(16) BF8 { BF4 a, b; };
struct alignas(16) I4 { int x, y, z, w; };

__device__ __forceinline__ unsigned short f2bf(float f) {
    union { float f; unsigned u; } v; v.f = f;
    unsigned u = v.u + (0x7FFFu + ((v.u >> 16) & 1u));   // RNE
    return (unsigned short)(u >> 16);
}

__device__ __forceinline__ void async_copy16(const unsigned short* g, unsigned short* l) {
    __builtin_amdgcn_global_load_lds(
        (const __attribute__((address_space(1))) void*)g,
        (__attribute__((address_space(3))) void*)l, 16, 0, 0);
}

__device__ __forceinline__ int find_expert(const int* __restrict__ bspe, int row0) {
    int e = 0, off = 0;
    #pragma unroll
    for (int i = 0; i < 8; ++i) {
        int s = bspe[i];
        if (row0 < off + s) { e = i; break; }
        off += s;
    }
    return e;
}

// ---------------------------------------------------------------------------
// fp32 -> bf16 conversion pass (memory-bound, ~503 MB traffic)
// ---------------------------------------------------------------------------
#define NX  33554432L   // 16384*2048
#define NUG 33554432L   // 2*8*1024*2048
#define NWD 16777216L   // 2048*8192

__global__ void cvt_all(const float* __restrict__ x, const float* __restrict__ wug,
                        const float* __restrict__ wd,
                        unsigned short* __restrict__ xbf, unsigned short* __restrict__ wugbf,
                        unsigned short* __restrict__ wdbf) {
    const long TOT8 = (NX + NUG + NWD) / 8;
    for (long i = (long)blockIdx.x * blockDim.x + threadIdx.x; i < TOT8;
         i += (long)gridDim.x * blockDim.x) {
        const long e0 = i * 8;
        const float* s; unsigned short* d;
        if (e0 < NX)            { s = x   + e0;              d = xbf   + e0; }
        else if (e0 < NX + NUG) { s = wug + (e0 - NX);       d = wugbf + (e0 - NX); }
        else                    { s = wd  + (e0 - NX - NUG); d = wdbf  + (e0 - NX - NUG); }
        const float4 a = *(const float4*)s;
        const float4 b = *(const float4*)(s + 4);
        BF8 o;
        o.a.x = f2bf(a.x); o.a.y = f2bf(a.y); o.a.z = f2bf(a.z); o.a.w = f2bf(a.w);
        o.b.x = f2bf(b.x); o.b.y = f2bf(b.y); o.b.z = f2bf(b.z); o.b.w = f2bf(b.w);
        *(BF8*)d = o;
    }
}

// ---------------------------------------------------------------------------
// m97-structure GEMMs: global_load_lds width-16, unpadded [128][32] bf16 LDS
// ---------------------------------------------------------------------------
__global__ __launch_bounds__(256) void moe_up_gate_v2(
    const unsigned short* __restrict__ xbf, const unsigned short* __restrict__ wugbf,
    const int* __restrict__ bspe, unsigned short* __restrict__ hbf) {
    __shared__ alignas(16) unsigned short As[BM * BK];
    __shared__ alignas(16) unsigned short Bs[BM * BK];

    const int t = threadIdx.x, lane = t & 63, w = t >> 6;
    const int wr = w >> 1, wc = w & 1;
    const int h0 = blockIdx.x * 64, row0 = blockIdx.y * BM;
    const int e = find_expert(bspe, row0);

    // staging geometry: issue i covers tile rows i*64 + w*16 + lane/4
    const int srow = lane >> 2;
    const int scol = (lane & 3) * 8;
    const long aoff0 = (long)(row0 + w * 16 + srow) * 2048 + scol;
    const long aoff1 = aoff0 + 64L * 2048;
    const int brow = w * 16 + srow;
    const long boff_up = ((long)e * 2048 + h0 + brow) * 2048 + scol;
    const long boff_gt = ((long)e * 2048 + 1024 + h0 + brow) * 2048 + scol;
    unsigned short* lA0 = As + w * 512;
    unsigned short* lA1 = As + 2048 + w * 512;
    unsigned short* lB0 = Bs + w * 512;
    unsigned short* lB1 = Bs + 2048 + w * 512;

    float4v acc[4][4];
    #pragma unroll
    for (int m = 0; m < 4; ++m)
        #pragma unroll
        for (int n = 0; n < 4; ++n) acc[m][n] = (float4v){0.f, 0.f, 0.f, 0.f};

    const int k8 = (lane >> 4) << 3;
    const int am = wr * 64 + (lane & 15);
    const int l15 = lane & 15;

    for (int k0 = 0; k0 < 2048; k0 += BK) {
        __syncthreads();
        async_copy16(xbf + aoff0 + k0, lA0);
        async_copy16(xbf + aoff1 + k0, lA1);
        async_copy16(wugbf + boff_up + k0, lB0);
        async_copy16(wugbf + boff_gt + k0, lB1);
        __syncthreads();

        short8 a[4], b[4];
        #pragma unroll
        for (int m = 0; m < 4; ++m)
            a[m] = *(const short8*)(As + (am + m * 16) * BK + k8);
        #pragma unroll
        for (int n = 0; n < 4; ++n) {
            const int rb = (n < 2) ? (wc * 32 + n * 16) : (64 + wc * 32 + (n - 2) * 16);
            b[n] = *(const short8*)(Bs + (rb + l15) * BK + k8);
        }
        #pragma unroll
        for (int m = 0; m < 4; ++m)
            #pragma unroll
            for (int n = 0; n < 4; ++n)
                acc[m][n] = __builtin_amdgcn_mfma_f32_16x16x32_bf16(a[m], b[n], acc[m][n], 0, 0, 0);
    }

    const int rbase = row0 + wr * 64 + (lane >> 4) * 4;
    const int cbase = h0 + wc * 32 + l15;
    #pragma unroll
    for (int m = 0; m < 4; ++m)
        #pragma unroll
        for (int n = 0; n < 2; ++n)
            #pragma unroll
            for (int q = 0; q < 4; ++q) {
                const float u = acc[m][n][q];
                const float g = acc[m][n + 2][q];
                const float s = u / (1.f + __expf(-u));
                hbf[(long)(rbase + m * 16 + q) * 1024 + cbase + n * 16] = f2bf(s * g);
            }
}

__global__ __launch_bounds__(256) void moe_down_v2(
    const unsigned short* __restrict__ hbf, const unsigned short* __restrict__ wdbf,
    const int* __restrict__ bspe, float* __restrict__ out) {
    __shared__ alignas(16) unsigned short As[BM * BK];
    __shared__ alignas(16) unsigned short Bs[BM * BK];

    const int t = threadIdx.x, lane = t & 63, w = t >> 6;
    const int wr = w >> 1, wc = w & 1;
    const int n0 = blockIdx.x * BM, row0 = blockIdx.y * BM;
    const int e = find_expert(bspe, row0);

    const int srow = lane >> 2;
    const int scol = (lane & 3) * 8;
    const long aoff0 = (long)(row0 + w * 16 + srow) * 1024 + scol;
    const long aoff1 = aoff0 + 64L * 1024;
    const long boff0 = (long)(n0 + w * 16 + srow) * 8192 + e * 1024 + scol;
    const long boff1 = boff0 + 64L * 8192;
    unsigned short* lA0 = As + w * 512;
    unsigned short* lA1 = As + 2048 + w * 512;
    unsigned short* lB0 = Bs + w * 512;
    unsigned short* lB1 = Bs + 2048 + w * 512;

    float4v acc[4][4];
    #pragma unroll
    for (int m = 0; m < 4; ++m)
        #pragma unroll
        for (int n = 0; n < 4; ++n) acc[m][n] = (float4v){0.f, 0.f, 0.f, 0.f};

    const int k8 = (lane >> 4) << 3;
    const int am = wr * 64 + (lane & 15);
    const int l15 = lane & 15;

    for (int k0 = 0; k0 < 1024; k0 += BK) {
        __syncthreads();
        async_copy16(hbf + aoff0 + k0, lA0);
        async_copy16(hbf + aoff1 + k0, lA1);
        async_copy16(wdbf + boff0 + k0, lB0);
        async_copy16(wdbf + boff1 + k0, lB1);
        __syncthreads();

        short8 a[4], b[4];
        #pragma unroll
        for (int m = 0; m < 4; ++m)
            a[m] = *(const short8*)(As + (am + m * 16) * BK + k8);
        #pragma unroll
        for (int n = 0; n < 4; ++n)
            b[n] = *(const short8*)(Bs + (wc * 64 + n * 16 + l15) * BK + k8);
        #pragma unroll
        for (int m = 0; m < 4; ++m)
            #pragma unroll
            for (int n = 0; n < 4; ++n)
                acc[m][n] = __builtin_amdgcn_mfma_f32_16x16x32_bf16(a[m], b[n], acc[m][n], 0, 0, 0);
    }

    const int rbase = row0 + wr * 64 + (lane >> 4) * 4;
    const int cbase = n0 + wc * 64 + l15;
    #pragma unroll
    for (int m = 0; m < 4; ++m)
        #pragma unroll
        for (int n = 0; n < 4; ++n)
            #pragma unroll
            for (int q = 0; q < 4; ++q)
                out[(long)(rbase + m * 16 + q) * 2048 + cbase + n * 16] = acc[m][n][q];
}

// ---------------------------------------------------------------------------
// Fallback (round-1, ws < 201.4 MB): fused-cvt VGPR-roundtrip staging
// ---------------------------------------------------------------------------
__device__ __forceinline__ void stage_f32_tile(const float* __restrict__ src, long ld,
                                               unsigned short* lds, int t) {
    const int rr = t >> 3;
    const int col = (t & 7) << 2;
    #pragma unroll
    for (int r = 0; r < 4; ++r) {
        const int row = rr + r * 32;
        const float4 v = *(const float4*)(src + (long)row * ld + col);
        BF4 o; o.x = f2bf(v.x); o.y = f2bf(v.y); o.z = f2bf(v.z); o.w = f2bf(v.w);
        *(BF4*)(lds + row * LDSK + col) = o;
    }
}

__global__ __launch_bounds__(256) void moe_up_gate_fb(
    const float* __restrict__ x, const float* __restrict__ wug,
    const int* __restrict__ bspe, unsigned short* __restrict__ hws) {
    __shared__ alignas(16) unsigned short As[BM * LDSK];
    __shared__ alignas(16) unsigned short Bs[BM * LDSK];
    const int t = threadIdx.x, lane = t & 63, w = t >> 6;
    const int wr = w >> 1, wc = w & 1;
    const int h0 = blockIdx.x * 64, row0 = blockIdx.y * BM;
    const int e = find_expert(bspe, row0);
    const float* abase = x + (long)row0 * 2048;
    const float* bup = wug + ((long)e * 2048 + h0) * 2048;
    const float* bgt = wug + ((long)e * 2048 + 1024 + h0) * 2048;
    float4v acc[4][4];
    #pragma unroll
    for (int m = 0; m < 4; ++m)
        #pragma unroll
        for (int n = 0; n < 4; ++n) acc[m][n] = (float4v){0.f, 0.f, 0.f, 0.f};
    const int k8 = (lane >> 4) << 3, am = wr * 64 + (lane & 15), l15 = lane & 15;
    for (int k0 = 0; k0 < 2048; k0 += BK) {
        __syncthreads();
        stage_f32_tile(abase + k0, 2048, As, t);
        {
            const int rr = t >> 3, col = (t & 7) << 2;
            #pragma unroll
            for (int r = 0; r < 4; ++r) {
                const int row = rr + r * 32;
                const float* p = (row < 64 ? bup + (long)row * 2048
                                           : bgt + (long)(row - 64) * 2048) + k0 + col;
                const float4 v = *(const float4*)p;
                BF4 o; o.x = f2bf(v.x); o.y = f2bf(v.y); o.z = f2bf(v.z); o.w = f2bf(v.w);
                *(BF4*)(Bs + row * LDSK + col) = o;
            }
        }
        __syncthreads();
        short8 a[4], b[4];
        #pragma unroll
        for (int m = 0; m < 4; ++m) a[m] = *(const short8*)(As + (am + m * 16) * LDSK + k8);
        #pragma unroll
        for (int n = 0; n < 4; ++n) {
            const int rb = (n < 2) ? (wc * 32 + n * 16) : (64 + wc * 32 + (n - 2) * 16);
            b[n] = *(const short8*)(Bs + (rb + l15) * LDSK + k8);
        }
        #pragma unroll
        for (int m = 0; m < 4; ++m)
            #pragma unroll
            for (int n = 0; n < 4; ++n)
                acc[m][n] = __builtin_amdgcn_mfma_f32_16x16x32_bf16(a[m], b[n], acc[m][n], 0, 0, 0);
    }
    const int rbase = row0 + wr * 64 + (lane >> 4) * 4;
    const int cbase = h0 + wc * 32 + l15;
    #pragma unroll
    for (int m = 0; m < 4; ++m)
        #pragma unroll
        for (int n = 0; n < 2; ++n)
            #pragma unroll
            for (int q = 0; q < 4; ++q) {
                const float u = acc[m][n][q], g = acc[m][n + 2][q];
                const float s = u / (1.f + __expf(-u));
                hws[(long)(rbase + m * 16 + q) * 1024 + cbase + n * 16] = f2bf(s * g);
            }
}

__global__ __launch_bounds__(256) void moe_down_fb(
    const unsigned short* __restrict__ hws, const float* __restrict__ wd,
    const int* __restrict__ bspe, float* __restrict__ out) {
    __shared__ alignas(16) unsigned short As[BM * LDSK];
    __shared__ alignas(16) unsigned short Bs[BM * LDSK];
    const int t = threadIdx.x, lane = t & 63, w = t >> 6;
    const int wr = w >> 1, wc = w & 1;
    const int n0 = blockIdx.x * BM, row0 = blockIdx.y * BM;
    const int e = find_expert(bspe, row0);
    const unsigned short* abase = hws + (long)row0 * 1024;
    const float* bbase = wd + (long)n0 * 8192 + e * 1024;
    float4v acc[4][4];
    #pragma unroll
    for (int m = 0; m < 4; ++m)
        #pragma unroll
        for (int n = 0; n < 4; ++n) acc[m][n] = (float4v){0.f, 0.f, 0.f, 0.f};
    const int k8 = (lane >> 4) << 3, am = wr * 64 + (lane & 15), l15 = lane & 15;
    for (int k0 = 0; k0 < 1024; k0 += BK) {
        __syncthreads();
        {
            const int row = t >> 2, col = (t & 3) << 3;
            #pragma unroll
            for (int r = 0; r < 2; ++r) {
                const I4 v = *(const I4*)(abase + (long)(row + r * 64) * 1024 + k0 + col);
                *(I4*)(As + (row + r * 64) * LDSK + col) = v;
            }
        }
        stage_f32_tile(bbase + k0, 8192, Bs, t);
        __syncthreads();
        short8 a[4], b[4];
        #pragma unroll
        for (int m = 0; m < 4; ++m) a[m] = *(const short8*)(As + (am + m * 16) * LDSK + k8);
        #pragma unroll
        for (int n = 0; n < 4; ++n) b[n] = *(const short8*)(Bs + (wc * 64 + n * 16 + l15) * LDSK + k8);
        #pragma unroll
        for (int m = 0; m < 4; ++m)
            #pragma unroll
            for (int n = 0; n < 4; ++n)
                acc[m][n] = __builtin_amdgcn_mfma_f32_16x16x32_bf16(a[m], b[n], acc[m][n], 0, 0, 0);
    }
    const int rbase = row0 + wr * 64 + (lane >> 4) * 4;
    const int cbase = n0 + wc * 64 + l15;
    #pragma unroll
    for (int m = 0; m < 4; ++m)
        #pragma unroll
        for (int n = 0; n < 4; ++n)
            #pragma unroll
            for (int q = 0; q < 4; ++q)
                out[(long)(rbase + m * 16 + q) * 2048 + cbase + n * 16] = acc[m][n][q];
}

extern "C" void kernel_launch(void* const* d_in, const int* in_sizes, int n_in,
                              void* d_out, int out_size, void* d_ws, size_t ws_size,
                              hipStream_t stream) {
    const float* x   = (const float*)d_in[0];
    const float* wug = (const float*)d_in[1];
    const float* wd  = (const float*)d_in[2];
    const int*  bspe = (const int*)d_in[3];
    float* out = (float*)d_out;

    const size_t need = (size_t)(NX + NUG + NWD + 16777216L) * 2;  // +h = 201.3 MB
    if (ws_size >= need) {
        unsigned short* xbf   = (unsigned short*)d_ws;
        unsigned short* wugbf = xbf + NX;
        unsigned short* wdbf  = wugbf + NUG;
        unsigned short* hbf   = wdbf + NWD;
        cvt_all<<<dim3(8192), dim3(256), 0, stream>>>(x, wug, wd, xbf, wugbf, wdbf);
        moe_up_gate_v2<<<dim3(16, 128), dim3(256), 0, stream>>>(xbf, wugbf, bspe, hbf);
        moe_down_v2  <<<dim3(16, 128), dim3(256), 0, stream>>>(hbf, wdbf, bspe, out);
    } else {
        unsigned short* hws = (unsigned short*)d_ws;
        moe_up_gate_fb<<<dim3(16, 128), dim3(256), 0, stream>>>(x, wug, bspe, hws);
        moe_down_fb  <<<dim3(16, 128), dim3(256), 0, stream>>>(hws, wd, bspe, out);
    }
}